// Round 1
// baseline (25227.333 us; speedup 1.0000x reference)
//
#include <hip/hip_runtime.h>
#include <hip/hip_fp16.h>

constexpr int kB = 128;
constexpr int kN = 1000;
constexpr int kE = 128;
constexpr int kH = 8;
constexpr int kT = 512;          // rollout block size
constexpr int kW = kT / 64;      // waves per block
constexpr float kScale = 0.25f;  // 1/sqrt(d), d = 16

__device__ __forceinline__ float h2fma2(unsigned a, unsigned b, float s) {
  float2 x = __half22float2(__builtin_bit_cast(__half2, a));
  float2 y = __half22float2(__builtin_bit_cast(__half2, b));
  return s + x.x * y.x + x.y * y.y;
}
__device__ __forceinline__ float dotu4(uint4 a, uint4 b) {
  float s = 0.f;
  s = h2fma2(a.x, b.x, s);
  s = h2fma2(a.y, b.y, s);
  s = h2fma2(a.z, b.z, s);
  s = h2fma2(a.w, b.w, s);
  return s;
}

// online-softmax / argmax combine. Tie on value -> smaller index wins
// (matches jnp.argmax first-occurrence semantics).
__device__ __forceinline__ void combine(float& m, float& s, int& a,
                                        float mo, float so, int ao) {
  bool take = (mo > m) || (mo == m && ao < a);
  float mw = take ? mo : m;
  float ml = take ? m : mo;
  float sw = take ? so : s;
  float sl = take ? s : so;
  s = sw + sl * __expf(ml - mw);
  m = mw;
  a = take ? ao : a;
}

// ---------------------------------------------------------------------------
// Kernel A: qkv = node_embeddings @ Wqkv + bqkv, split to k/v/logit_k, f16.
// Block: 384 threads (one output column each), 16 nodes per block.
// ---------------------------------------------------------------------------
__global__ __launch_bounds__(384) void qkv_kernel(
    const float* __restrict__ ne, const float* __restrict__ Wqkv,
    const float* __restrict__ bqkv, __half* __restrict__ kh,
    __half* __restrict__ vh, __half* __restrict__ lkh) {
  __shared__ float rows[16 * kE];
  int b = blockIdx.x;
  int n0 = blockIdx.y * 16;
  int ntile = min(16, kN - n0);
  int tid = threadIdx.x;

  for (int idx = tid; idx < ntile * kE; idx += 384)
    rows[idx] = ne[(b * kN + n0) * kE + idx];
  __syncthreads();

  int j = tid;  // 0..383
  float acc[16];
#pragma unroll
  for (int r = 0; r < 16; ++r) acc[r] = 0.f;
  for (int i = 0; i < kE; ++i) {
    float w = Wqkv[i * (3 * kE) + j];
#pragma unroll
    for (int r = 0; r < 16; ++r) acc[r] += rows[r * kE + i] * w;
  }
  float bias = bqkv[j];
  __half* dst;
  int col;
  if (j < kE) { dst = kh; col = j; }
  else if (j < 2 * kE) { dst = vh; col = j - kE; }
  else { dst = lkh; col = j - 2 * kE; }
  for (int r = 0; r < ntile; ++r)
    dst[(b * kN + n0 + r) * kE + col] = __float2half(acc[r] + bias);
}

// ---------------------------------------------------------------------------
// Kernel B: qbase[b] = ge@Wfix + bfix + first@Wstep_top + bstep  (fp32)
// ---------------------------------------------------------------------------
__global__ __launch_bounds__(128) void qbase_kernel(
    const float* __restrict__ ne, const float* __restrict__ ge,
    const float* __restrict__ Wfix, const float* __restrict__ bfix,
    const float* __restrict__ Wstep, const float* __restrict__ bstep,
    float* __restrict__ qbase) {
  __shared__ float g[kE], f[kE];
  int b = blockIdx.x, e = threadIdx.x;
  g[e] = ge[b * kE + e];
  f[e] = ne[b * kN * kE + e];  // node 0
  __syncthreads();
  float acc = bfix[e] + bstep[e];
  for (int i = 0; i < kE; ++i)
    acc += g[i] * Wfix[i * kE + e] + f[i] * Wstep[i * kE + e];
  qbase[b * kE + e] = acc;
}

// ---------------------------------------------------------------------------
// Kernel C: the 999-step sequential rollout. One block per batch element.
// ---------------------------------------------------------------------------
__global__ __launch_bounds__(kT) void rollout_kernel(
    const float* __restrict__ ne, const float* __restrict__ Wstep,
    const float* __restrict__ Wmlp, const float* __restrict__ bmlp,
    const __half* __restrict__ kh, const __half* __restrict__ vh,
    const __half* __restrict__ lkh, const float* __restrict__ qbase,
    float* __restrict__ out) {
  __shared__ float p[kH * kN];       // unnormalized attention probs, 32 KB
  __shared__ float parts[8 * kE];    // matvec / ctx partials (reused)
  __shared__ float lastv[kE];
  __shared__ float qb[kE];
  __shared__ float ctx[kE];
  __shared__ __align__(16) __half qh[kE];
  __shared__ __align__(16) __half xh[kE];
  __shared__ float invsum[kH];
  __shared__ float redSum[kW][kH];
  __shared__ float redM[kW], redS[kW];
  __shared__ int redI[kW];
  __shared__ unsigned char mask[kN];
  __shared__ int cur_s;
  __shared__ float total_s;

  int b = blockIdx.x;
  int tid = threadIdx.x;
  int lane = tid & 63;
  int wave = tid >> 6;

  const float* Wbot = Wstep + kE * kE;  // rows for `last`
  const __half* khb = kh + (size_t)b * kN * kE;
  const __half* vhb = vh + (size_t)b * kN * kE;
  const __half* lkb = lkh + (size_t)b * kN * kE;
  const float* neb = ne + (size_t)b * kN * kE;

  for (int i = tid; i < kN; i += kT) mask[i] = 0;
  if (tid < kE) qb[tid] = qbase[b * kE + tid];
  if (tid == 0) { mask[0] = 1; cur_s = 0; total_s = 0.f; }
  __syncthreads();

  for (int step = 0; step < kN - 1; ++step) {
    // ---- 1. fetch embedding of current node
    int cur = cur_s;
    if (tid < kE) lastv[tid] = neb[cur * kE + tid];
    __syncthreads();

    // ---- 2. q partials: q = qbase + last @ Wbot
    {
      int e = tid & 127, c = tid >> 7;  // c in 0..3, 32 i's each
      float acc = 0.f;
      int i0 = c * 32;
#pragma unroll 8
      for (int i = i0; i < i0 + 32; ++i) acc += lastv[i] * Wbot[i * kE + e];
      parts[c * kE + e] = acc;
    }
    __syncthreads();

    // ---- 3. q combine -> f16
    if (tid < kE) {
      float v = qb[tid] + parts[tid] + parts[kE + tid] + parts[2 * kE + tid] +
                parts[3 * kE + tid];
      qh[tid] = __float2half(v);
    }
    __syncthreads();

    // ---- 4. attention scores + exp (no max-subtract: scores are tiny)
    float sums[kH];
#pragma unroll
    for (int h = 0; h < kH; ++h) sums[h] = 0.f;
    for (int n = tid; n < kN; n += kT) {
      if (mask[n]) {
#pragma unroll
        for (int h = 0; h < kH; ++h) p[h * kN + n] = 0.f;
      } else {
        const uint4* krow = (const uint4*)(khb + (size_t)n * kE);
        const uint4* q4 = (const uint4*)qh;
#pragma unroll
        for (int h = 0; h < kH; ++h) {
          float s = dotu4(krow[2 * h], q4[2 * h]) +
                    dotu4(krow[2 * h + 1], q4[2 * h + 1]);
          float pv = __expf(s * kScale);
          p[h * kN + n] = pv;
          sums[h] += pv;
        }
      }
    }
#pragma unroll
    for (int h = 0; h < kH; ++h) {
      float v = sums[h];
      for (int off = 32; off; off >>= 1) v += __shfl_xor(v, off);
      sums[h] = v;
    }
    if (lane == 0) {
#pragma unroll
      for (int h = 0; h < kH; ++h) redSum[wave][h] = sums[h];
    }
    __syncthreads();

    // ---- 5. finalize per-head softmax denominators
    if (tid < kH) {
      float s = 0.f;
#pragma unroll
      for (int w = 0; w < kW; ++w) s += redSum[w][tid];
      invsum[tid] = 1.f / s;
    }
    __syncthreads();

    // ---- 6. ctx partials: wave w sums nodes [125w, 125w+125)
    {
      int pe = lane;        // element pair (2pe, 2pe+1)
      int h = pe >> 3;      // head of this pair
      float a0 = 0.f, a1 = 0.f;
      int n0 = wave * 125;
#pragma unroll 5
      for (int n = n0; n < n0 + 125; ++n) {
        float w_ = p[h * kN + n];
        float2 vf =
            __half22float2(((const __half2*)(vhb + (size_t)n * kE))[pe]);
        a0 += w_ * vf.x;
        a1 += w_ * vf.y;
      }
      *(float2*)(parts + wave * kE + 2 * pe) = make_float2(a0, a1);
    }
    __syncthreads();

    // ---- 7. ctx combine + normalize
    if (tid < kE) {
      float s = 0.f;
#pragma unroll
      for (int w = 0; w < 8; ++w) s += parts[w * kE + tid];
      ctx[tid] = s * invsum[tid >> 4];
    }
    __syncthreads();

    // ---- 8. x partials: x = ctx @ Wmlp + bmlp
    {
      int e = tid & 127, c = tid >> 7;
      float acc = 0.f;
      int i0 = c * 32;
#pragma unroll 8
      for (int i = i0; i < i0 + 32; ++i) acc += ctx[i] * Wmlp[i * kE + e];
      parts[c * kE + e] = acc;
    }
    __syncthreads();

    // ---- 9. x combine -> f16
    if (tid < kE) {
      float v = bmlp[tid] + parts[tid] + parts[kE + tid] + parts[2 * kE + tid] +
                parts[3 * kE + tid];
      xh[tid] = __float2half(v);
    }
    __syncthreads();

    // ---- 10. logits + online log-softmax + argmax
    float m = -1e30f, ssum = 0.f;
    int arg = 0x7fffffff;
    for (int n = tid; n < kN; n += kT) {
      if (mask[n]) continue;
      const uint4* lrow = (const uint4*)(lkb + (size_t)n * kE);
      const uint4* x4 = (const uint4*)xh;
      float s = 0.f;
#pragma unroll
      for (int j = 0; j < 16; ++j) s += dotu4(lrow[j], x4[j]);
      float l = tanhf(s * kScale) * 10.f;
      combine(m, ssum, arg, l, 1.f, n);
    }
    for (int off = 32; off; off >>= 1) {
      float mo = __shfl_xor(m, off);
      float so = __shfl_xor(ssum, off);
      int ao = __shfl_xor(arg, off);
      combine(m, ssum, arg, mo, so, ao);
    }
    if (lane == 0) { redM[wave] = m; redS[wave] = ssum; redI[wave] = arg; }
    __syncthreads();

    // ---- 11. pick action, update state
    if (tid == 0) {
      float M = redM[0], S = redS[0];
      int A = redI[0];
      for (int w = 1; w < kW; ++w) combine(M, S, A, redM[w], redS[w], redI[w]);
      // chosen logit == M, so log_p[act] = M - (M + log S) = -log S
      total_s += -logf(S);
      cur_s = A;
      mask[A] = 1;
    }
    __syncthreads();
  }
  if (tid == 0) out[b] = total_s;
}

// ---------------------------------------------------------------------------
extern "C" void kernel_launch(void* const* d_in, const int* in_sizes, int n_in,
                              void* d_out, int out_size, void* d_ws,
                              size_t ws_size, hipStream_t stream) {
  const float* ne = (const float*)d_in[0];
  const float* ge = (const float*)d_in[1];
  const float* Wqkv = (const float*)d_in[2];
  const float* bqkv = (const float*)d_in[3];
  const float* Wfix = (const float*)d_in[4];
  const float* bfix = (const float*)d_in[5];
  const float* Wstep = (const float*)d_in[6];
  const float* bstep = (const float*)d_in[7];
  const float* Wmlp = (const float*)d_in[8];
  const float* bmlp = (const float*)d_in[9];
  float* out = (float*)d_out;

  size_t nkv = (size_t)kB * kN * kE;
  __half* kh = (__half*)d_ws;
  __half* vh = kh + nkv;
  __half* lkh = vh + nkv;
  float* qbase = (float*)(lkh + nkv);  // 98,304,000-byte offset, 16B aligned

  qkv_kernel<<<dim3(kB, (kN + 15) / 16), 384, 0, stream>>>(ne, Wqkv, bqkv, kh,
                                                           vh, lkh);
  qbase_kernel<<<kB, kE, 0, stream>>>(ne, ge, Wfix, bfix, Wstep, bstep, qbase);
  rollout_kernel<<<kB, kT, 0, stream>>>(ne, Wstep, Wmlp, bmlp, kh, vh, lkh,
                                        qbase, out);
}